// Round 20
// baseline (261.663 us; speedup 1.0000x reference)
//
#include <hip/hip_runtime.h>
#include <stdint.h>

// S3FD anchor assignment — wave-uniform cell walk, round 20.
// d_in[0]: anchor [N,4] f32, d_in[1]: gt [M,4] f32. d_out: assign [N] int32.
//
// Rounds 16-19 post-mortem: the pair walk never exceeded VALUBusy 16% at any
// occupancy (32-70%) — the stall is intra-wave: lanes in original anchor
// order walk DIFFERENT cells (divergent loop lengths, 64-way random LDS
// gathers, divergent inserts). Round 20: bin anchor INDICES by cell (4B
// scatter, padded cursors, fixed CAP slots — no hist/scan), then ONE BLOCK
// PER CELL so the GT loop is wave-uniform: same cnt/k/m for all lanes,
// s_gb/s_ga/tbl-prefilter reads are conflict-free broadcasts, divergence
// only on the rare insert mask. Per-pair math, key encodings, seeds, shadow
// merge, and claims byte-identical to the passing rounds 16/19.
//
// Key encoding (exact jax semantics), per-GT top-3:
//   key = (iou_bits << 32) | ~anchor_idx    (stable top_k: higher iou, then
//                                            lower anchor index wins)
// Seeds (0,~0),(0,~1),(0,~2) reproduce the reference's index-ordered zero
// fill (benign-duplication argument proven rounds 8-19).

typedef unsigned int u32;
typedef unsigned char u8;
typedef unsigned long long u64;

#define POS_THRESH 0.5f
#define NEG_THRESH 0.3f
#define CLAIM_THRESH 0.1f

constexpr int NCX = 32, NCY = 32, NCELL = NCX * NCY;  // 32x32 cells, 32 px
constexpr float INV_CELL = 0.03125f;                  // 1/32
constexpr float MARGIN = 64.5f;   // max anchor half-extent (<64.001) + slack
constexpr int MPAD = 256;         // padded GT count (M = 200); id stride
constexpr int HSLOTS = 1024;      // claims hash table slots
constexpr int NSHADOW = 16;       // shadow copies of final3
constexpr int SSTRIDE = 8;        // u64 per (GT,shadow) slot = 64B line
constexpr int CPAD = 16;          // u32 stride per cursor = one 64B line
constexpr int CAP = 2048;         // anchor slots per cell (lambda ~488; 24σ)

// IoU expression verbatim from the passing rounds (numpy-exact).
#define IOU_EVAL(a, areaA, g, areaG, inter, iou) {                \
    float ltx = fmaxf(a.x, g.x), lty = fmaxf(a.y, g.y);           \
    float rbx = fminf(a.z, g.z), rby = fminf(a.w, g.w);           \
    float ww = fmaxf(rbx - ltx, 0.0f);                            \
    float hh = fmaxf(rby - lty, 0.0f);                            \
    inter = ww * hh;                                              \
    iou = 0.0f;                                                   \
    if (inter > 0.0f) iou = inter / ((areaA + areaG) - inter);    \
}

#define INS3(t0, t1, t2, k) do {                                  \
    if ((k) > (t2)) {                                             \
        if ((k) > (t0))      { t2 = t1; t1 = t0; t0 = (k); }      \
        else if ((k) > (t1)) { t2 = t1; t1 = (k); }               \
        else                 { t2 = (k); }                        \
    } } while (0)

__device__ __forceinline__ int cell_of(const float4 a) {
    float cx = 0.5f * (a.x + a.z);
    float cy = 0.5f * (a.y + a.w);
    int ix = (int)(cx * INV_CELL);
    int iy = (int)(cy * INV_CELL);
    ix = ix < 0 ? 0 : (ix > NCX - 1 ? NCX - 1 : ix);
    iy = iy < 0 ? 0 : (iy > NCY - 1 ? NCY - 1 : iy);
    return iy * NCX + ix;
}

__device__ __forceinline__ void gt_range(const float4 g, int& clx, int& chx,
                                         int& cly, int& chy) {
    clx = (int)floorf((g.x - MARGIN) * INV_CELL);
    chx = (int)floorf((g.z + MARGIN) * INV_CELL);
    cly = (int)floorf((g.y - MARGIN) * INV_CELL);
    chy = (int)floorf((g.w + MARGIN) * INV_CELL);
    clx = clx < 0 ? 0 : (clx > NCX - 1 ? NCX - 1 : clx);
    chx = chx < 0 ? 0 : (chx > NCX - 1 ? NCX - 1 : chx);
    cly = cly < 0 ? 0 : (cly > NCY - 1 ? NCY - 1 : cly);
    chy = chy < 0 ? 0 : (chy > NCY - 1 ? NCY - 1 : chy);
}

// Concurrent sorted top-3 insert: atomicMax cascade (proven rounds 15-19).
#define CASCADE3(p0, p1, p2, key) {                               \
    u64 x_ = (key);                                               \
    u64 o_ = atomicMax(&(p0), x_); x_ = o_ < x_ ? o_ : x_;        \
    o_ = atomicMax(&(p1), x_); x_ = o_ < x_ ? o_ : x_;            \
    atomicMax(&(p2), x_);                                         \
}

// ---------------------------------------------------------------------------
// Prep (1 block): per-cell GT lists (u8 ids, stride MPAD) + zero cursors
// and shadow tables.
__global__ void __launch_bounds__(256) k_prep(
    const float4* __restrict__ gt, u32* __restrict__ gtCnt,
    u8* __restrict__ gtIds, u32* __restrict__ cursor,
    u64* __restrict__ shadow3, int M)
{
    __shared__ u32 l_cnt[NCELL];
    const int tid = threadIdx.x;
    for (int c = tid; c < NCELL; c += 256) l_cnt[c] = 0;

    for (int e = tid; e < NCELL * CPAD; e += 256) cursor[e] = 0;
    for (int e = tid; e < M * NSHADOW; e += 256) {
        u64* slot = shadow3 + (size_t)e * SSTRIDE;
        slot[0] = 0; slot[1] = 0; slot[2] = 0;
    }
    __syncthreads();

    if (tid < M) {
        float4 g = gt[tid];
        int clx, chx, cly, chy;
        gt_range(g, clx, chx, cly, chy);
        for (int iy = cly; iy <= chy; ++iy)
            for (int ix = clx; ix <= chx; ++ix) {
                int c = iy * NCX + ix;
                u32 slot = atomicAdd(&l_cnt[c], 1u);
                gtIds[(size_t)c * MPAD + slot] = (u8)tid;
            }
    }
    __syncthreads();
    for (int c = tid; c < NCELL; c += 256) gtCnt[c] = l_cnt[c];
}

// ---------------------------------------------------------------------------
// Scatter anchor INDICES into per-cell slot arrays (padded atomic cursors).
__global__ void __launch_bounds__(256) k_scatidx(
    const float4* __restrict__ anchor, u32* __restrict__ cursor,
    int* __restrict__ binnedIdx, int N)
{
    int i = blockIdx.x * 256 + threadIdx.x;
    if (i >= N) return;
    int c = cell_of(anchor[i]);
    u32 pos = atomicAdd(&cursor[c * CPAD], 1u);
    binnedIdx[(size_t)c * CAP + pos] = i;
}

// ---------------------------------------------------------------------------
// Walk (NCELL blocks x 256): block = cell. All lanes share the cell's GT
// list -> wave-uniform inner loop, broadcast LDS reads, no divergence
// except the rare insert mask. Base assignment (register max) + per-GT
// top-3 into the cell's LDS table. Epilogue: merge into shadow.
__global__ void __launch_bounds__(256) k_walk(
    const float4* __restrict__ anchor, const float4* __restrict__ gt,
    const u32* __restrict__ gtCnt, const u8* __restrict__ gtIds,
    const u32* __restrict__ cursor, const int* __restrict__ binnedIdx,
    u64* __restrict__ shadow3, int* __restrict__ out, int M)
{
    __shared__ float4 s_gb[MPAD];
    __shared__ float  s_ga[MPAD];
    __shared__ int    s_id[MPAD];
    __shared__ u64    tbl[3 * MPAD];
    const int c   = blockIdx.x;
    const int tid = threadIdx.x;
    const int cnt = (int)gtCnt[c];

    if (tid < cnt) {                       // cnt <= M=200 < 256: one pass
        int m = gtIds[(size_t)c * MPAD + tid];
        float4 g = gt[m];
        s_gb[tid] = g;
        s_ga[tid] = (g.z - g.x) * (g.w - g.y);
        s_id[tid] = m;
    }
    for (int e = tid; e < 3 * MPAD; e += 256) tbl[e] = 0;
    const int nA = (int)cursor[c * CPAD];
    __syncthreads();

    for (int p = tid; p < nA; p += 256) {
        int idx = binnedIdx[(size_t)c * CAP + p];
        float4 a = anchor[idx];            // L2 gather, 1 per ~cnt IoUs
        float area_a = (a.z - a.x) * (a.w - a.y);
        u32 nai = ~(u32)idx;

        u64 best = 0;
        for (int k = 0; k < cnt; ++k) {    // wave-uniform loop
            float4 g = s_gb[k];            // broadcast, conflict-free
            float ag = s_ga[k];
            float inter, iou;
            IOU_EVAL(a, area_a, g, ag, inter, iou);
            if (inter > 0.0f) {
                u32 ib = __float_as_uint(iou);
                u64 kb = ((u64)ib << 32) | (~(u32)s_id[k]);
                best = kb > best ? kb : best;
                u64 kt = ((u64)ib << 32) | nai;
                if (kt > tbl[k * 3 + 2])   // broadcast prefilter, safe
                    CASCADE3(tbl[k * 3 + 0], tbl[k * 3 + 1],
                             tbl[k * 3 + 2], kt);
            }
        }
        u32 ib = (u32)(best >> 32);
        int v = -2;
        if (ib < __float_as_uint(NEG_THRESH)) v = -1;   // max iou < 0.3
        if (ib > __float_as_uint(POS_THRESH)) v = (int)(~(u32)best);
        out[idx] = v;
    }
    __syncthreads();

    // merge the cell's per-GT top-3 -> this block's shadow copy
    const int s = blockIdx.x & (NSHADOW - 1);
    for (int e = tid; e < 3 * cnt; e += 256) {
        u64 v = tbl[e];
        if ((u32)(v >> 32) == 0) continue;     // zero-iou: seeded in claims
        int m = s_id[e / 3];
        u64* g3 = shadow3 + ((size_t)m * NSHADOW + s) * SSTRIDE;
        if (v <= g3[2]) continue;              // racy prefilter, safe
        CASCADE3(g3[0], g3[1], g3[2], v);
    }
}

// ---------------------------------------------------------------------------
// Claims: accumulate per-GT top-3 from seeds + 16 shadows, then forced-claim
// scatter-max via the proven 1024-slot LDS hash (tag CAS + 64-bit atomicMax).
// claim key = (anchor<<32)|(gt+1); max key == last-writer gt == reference.
__global__ void __launch_bounds__(256) k_claims(
    const u64* __restrict__ shadow3, int* __restrict__ out, int M)
{
    __shared__ u64 s_key[3 * MPAD];
    __shared__ u64 h_val[HSLOTS];
    __shared__ u32 h_tag[HSLOTS];   // anchor+1; 0 = empty
    const int tid = threadIdx.x;

    for (int i = tid; i < HSLOTS; i += 256) { h_val[i] = 0; h_tag[i] = 0; }

    if (tid < M) {
        // accumulators start at the zero-iou seeds (index-ordered fill)
        u64 q0 = 0x00000000FFFFFFFFULL;   // (iou=0, ~0)
        u64 q1 = 0x00000000FFFFFFFEULL;   // (iou=0, ~1)
        u64 q2 = 0x00000000FFFFFFFDULL;   // (iou=0, ~2)
        const u64* base = shadow3 + (size_t)tid * NSHADOW * SSTRIDE;
        for (int s = 0; s < NSHADOW; ++s) {
            const u64* p = base + (size_t)s * SSTRIDE;
            INS3(q0, q1, q2, p[0]);
            INS3(q0, q1, q2, p[1]);
            INS3(q0, q1, q2, p[2]);
        }

        float v0 = __uint_as_float((u32)(q0 >> 32));
        float v1 = __uint_as_float((u32)(q1 >> 32));
        float v2 = __uint_as_float((u32)(q2 >> 32));
        u32 a0 = ~(u32)q0;
        u32 a1 = ~(u32)q1;
        u32 a2 = ~(u32)q2;

        int npos = (v0 > POS_THRESH) + (v1 > POS_THRESH) + (v2 > POS_THRESH);
        bool low = npos < 3;

        s_key[tid * 3 + 0] = ((u64)a0 << 32) | (u32)(tid + 1);   // k==0 forced
        s_key[tid * 3 + 1] = (low && v1 > CLAIM_THRESH)
            ? (((u64)a1 << 32) | (u32)(tid + 1)) : 0ULL;
        s_key[tid * 3 + 2] = (low && v2 > CLAIM_THRESH)
            ? (((u64)a2 << 32) | (u32)(tid + 1)) : 0ULL;
    }
    __syncthreads();

    const int tote = 3 * M;
    // insert: claim slot by anchor tag, atomicMax the claim key
    for (int e = tid; e < tote; e += 256) {
        u64 my = s_key[e];
        if (my == 0) continue;
        u32 myA = (u32)(my >> 32);
        u32 slot = (myA * 2654435761u) & (HSLOTS - 1);
        while (true) {
            u32 prev = atomicCAS(&h_tag[slot], 0u, myA + 1u);
            if (prev == 0u || prev == myA + 1u) {
                atomicMax(&h_val[slot], my);
                break;
            }
            slot = (slot + 1) & (HSLOTS - 1);
        }
    }
    __syncthreads();
    // resolve: claim wins iff it holds the max key for its anchor
    for (int e = tid; e < tote; e += 256) {
        u64 my = s_key[e];
        if (my == 0) continue;
        u32 myA = (u32)(my >> 32);
        u32 slot = (myA * 2654435761u) & (HSLOTS - 1);
        while (h_tag[slot] != myA + 1u) slot = (slot + 1) & (HSLOTS - 1);
        if (h_val[slot] == my) out[myA] = (int)(my & 0xffffffffULL) - 1;
    }
}

// ---------------------------------------------------------------------------
extern "C" void kernel_launch(void* const* d_in, const int* in_sizes, int n_in,
                              void* d_out, int out_size, void* d_ws, size_t ws_size,
                              hipStream_t stream) {
    const float4* anchor = (const float4*)d_in[0];
    const float4* gt     = (const float4*)d_in[1];
    int N = in_sizes[0] / 4;
    int M = in_sizes[1] / 4;
    int* out = (int*)d_out;

    // workspace layout (~8.6 MB; ws_size ~= 256 MB)
    char* ws = (char*)d_ws;
    size_t off = 0;
    auto alloc = [&](size_t bytes, size_t align) -> void* {
        off = (off + align - 1) / align * align;
        void* p = ws + off;
        off += bytes;
        return p;
    };
    u32* gtCnt     = (u32*)alloc(NCELL * 4, 64);
    u32* cursor    = (u32*)alloc((size_t)NCELL * CPAD * 4, 64);
    u64* shadow3   = (u64*)alloc((size_t)MPAD * NSHADOW * SSTRIDE * 8, 64);
    u8*  gtIds     = (u8*)alloc((size_t)NCELL * MPAD, 16);
    int* binnedIdx = (int*)alloc((size_t)NCELL * CAP * 4, 16);

    int nb = (N + 255) / 256;
    k_prep<<<1, 256, 0, stream>>>(gt, gtCnt, gtIds, cursor, shadow3, M);
    k_scatidx<<<nb, 256, 0, stream>>>(anchor, cursor, binnedIdx, N);
    k_walk<<<NCELL, 256, 0, stream>>>(anchor, gt, gtCnt, gtIds, cursor,
                                      binnedIdx, shadow3, out, M);
    k_claims<<<1, 256, 0, stream>>>(shadow3, out, M);
}

// Round 21
// 194.421 us; speedup vs baseline: 1.3459x; 1.3459x over previous
//
#include <hip/hip_runtime.h>
#include <stdint.h>

// S3FD anchor assignment — per-cell walk, GT-per-lane registers, round 21.
// d_in[0]: anchor [N,4] f32, d_in[1]: gt [M,4] f32. d_out: assign [N] int32.
//
// Round 20 post-mortem: wave-uniform walk hit VALU 40% (best) but regressed
// to 213 us — uniform k made ALL 64 lanes cascade into the SAME tbl[k*3+..]
// LDS words (same-address atomic serialization). Round 21: keep the per-cell
// block but TRANSPOSE in-wave (round 3's proven layout): lane owns GT slot
// lane+64r (r gated by uniform cnt>64r scalar branches); anchors broadcast
// from a 256-deep LDS stage; each lane's IoU + top-3 insert is pure REGISTER
// work (no atomics, no LDS in the pair loop). Per-anchor argmax = 6-step u64
// (iou_bits,~m) butterfly — exact first-max, order-independent. Register
// top-3 cascades directly into the proven 16-shadow global table.
// prep/scatidx/claims byte-identical to round 20.
//
// Key encoding (exact jax semantics), per-GT top-3:
//   key = (iou_bits << 32) | ~anchor_idx    (stable top_k: higher iou, then
//                                            lower anchor index wins)
// Seeds (0,~0),(0,~1),(0,~2) reproduce the reference's index-ordered zero
// fill (benign-duplication argument proven rounds 8-20).

typedef unsigned int u32;
typedef unsigned char u8;
typedef unsigned long long u64;

#define POS_THRESH 0.5f
#define NEG_THRESH 0.3f
#define CLAIM_THRESH 0.1f

constexpr int NCX = 32, NCY = 32, NCELL = NCX * NCY;  // 32x32 cells, 32 px
constexpr float INV_CELL = 0.03125f;                  // 1/32
constexpr float MARGIN = 64.5f;   // max anchor half-extent (<64.001) + slack
constexpr int MPAD = 256;         // padded GT count (M = 200); id stride
constexpr int HSLOTS = 1024;      // claims hash table slots
constexpr int NSHADOW = 16;       // shadow copies of final3
constexpr int SSTRIDE = 8;        // u64 per (GT,shadow) slot = 64B line
constexpr int CPAD = 16;          // u32 stride per cursor = one 64B line
constexpr int CAP = 2048;         // anchor slots per cell (lambda ~488)

#define INS3(t0, t1, t2, k) do {                                  \
    if ((k) > (t2)) {                                             \
        if ((k) > (t0))      { t2 = t1; t1 = t0; t0 = (k); }      \
        else if ((k) > (t1)) { t2 = t1; t1 = (k); }               \
        else                 { t2 = (k); }                        \
    } } while (0)

__device__ __forceinline__ u64 shfl_xor_u64(u64 x, int mask) {
    int lo = __shfl_xor((int)(u32)x, mask, 64);
    int hi = __shfl_xor((int)(u32)(x >> 32), mask, 64);
    return ((u64)(u32)hi << 32) | (u32)lo;
}

__device__ __forceinline__ int cell_of(const float4 a) {
    float cx = 0.5f * (a.x + a.z);
    float cy = 0.5f * (a.y + a.w);
    int ix = (int)(cx * INV_CELL);
    int iy = (int)(cy * INV_CELL);
    ix = ix < 0 ? 0 : (ix > NCX - 1 ? NCX - 1 : ix);
    iy = iy < 0 ? 0 : (iy > NCY - 1 ? NCY - 1 : iy);
    return iy * NCX + ix;
}

__device__ __forceinline__ void gt_range(const float4 g, int& clx, int& chx,
                                         int& cly, int& chy) {
    clx = (int)floorf((g.x - MARGIN) * INV_CELL);
    chx = (int)floorf((g.z + MARGIN) * INV_CELL);
    cly = (int)floorf((g.y - MARGIN) * INV_CELL);
    chy = (int)floorf((g.w + MARGIN) * INV_CELL);
    clx = clx < 0 ? 0 : (clx > NCX - 1 ? NCX - 1 : clx);
    chx = chx < 0 ? 0 : (chx > NCX - 1 ? NCX - 1 : chx);
    cly = cly < 0 ? 0 : (cly > NCY - 1 ? NCY - 1 : cly);
    chy = chy < 0 ? 0 : (chy > NCY - 1 ? NCY - 1 : chy);
}

// Concurrent sorted top-3 insert: atomicMax cascade (proven rounds 15-20).
#define CASCADE3(p0, p1, p2, key) {                               \
    u64 x_ = (key);                                               \
    u64 o_ = atomicMax(&(p0), x_); x_ = o_ < x_ ? o_ : x_;        \
    o_ = atomicMax(&(p1), x_); x_ = o_ < x_ ? o_ : x_;            \
    atomicMax(&(p2), x_);                                         \
}

// ---------------------------------------------------------------------------
// Prep (1 block): per-cell GT lists (u8 ids, stride MPAD) + zero cursors
// and shadow tables.
__global__ void __launch_bounds__(256) k_prep(
    const float4* __restrict__ gt, u32* __restrict__ gtCnt,
    u8* __restrict__ gtIds, u32* __restrict__ cursor,
    u64* __restrict__ shadow3, int M)
{
    __shared__ u32 l_cnt[NCELL];
    const int tid = threadIdx.x;
    for (int c = tid; c < NCELL; c += 256) l_cnt[c] = 0;

    for (int e = tid; e < NCELL * CPAD; e += 256) cursor[e] = 0;
    for (int e = tid; e < M * NSHADOW; e += 256) {
        u64* slot = shadow3 + (size_t)e * SSTRIDE;
        slot[0] = 0; slot[1] = 0; slot[2] = 0;
    }
    __syncthreads();

    if (tid < M) {
        float4 g = gt[tid];
        int clx, chx, cly, chy;
        gt_range(g, clx, chx, cly, chy);
        for (int iy = cly; iy <= chy; ++iy)
            for (int ix = clx; ix <= chx; ++ix) {
                int c = iy * NCX + ix;
                u32 slot = atomicAdd(&l_cnt[c], 1u);
                gtIds[(size_t)c * MPAD + slot] = (u8)tid;
            }
    }
    __syncthreads();
    for (int c = tid; c < NCELL; c += 256) gtCnt[c] = l_cnt[c];
}

// ---------------------------------------------------------------------------
// Scatter anchor INDICES into per-cell slot arrays (padded atomic cursors).
__global__ void __launch_bounds__(256) k_scatidx(
    const float4* __restrict__ anchor, u32* __restrict__ cursor,
    int* __restrict__ binnedIdx, int N)
{
    int i = blockIdx.x * 256 + threadIdx.x;
    if (i >= N) return;
    int c = cell_of(anchor[i]);
    u32 pos = atomicAdd(&cursor[c * CPAD], 1u);
    binnedIdx[(size_t)c * CAP + pos] = i;
}

// ---------------------------------------------------------------------------
// Walk (NCELL blocks x 256): block = cell; LANE OWNS GT SLOT lane+64r (all
// state in registers). Anchors staged 256-deep in LDS and broadcast; per
// anchor each lane does one register IoU + register top-3 insert per live
// slot; per-anchor argmax via u64 (iou_bits,~m) butterfly. Epilogue: lanes
// cascade their register top-3 into shadow (blockIdx & 15), prefiltered.
__global__ void __launch_bounds__(256) k_walk(
    const float4* __restrict__ anchor, const float4* __restrict__ gt,
    const u32* __restrict__ gtCnt, const u8* __restrict__ gtIds,
    const u32* __restrict__ cursor, const int* __restrict__ binnedIdx,
    u64* __restrict__ shadow3, int* __restrict__ out, int M)
{
    __shared__ float4 s_a[256];
    __shared__ float  s_area[256];
    __shared__ int    s_idx[256];
    const int c    = blockIdx.x;
    const int tid  = threadIdx.x;
    const int lane = tid & 63;
    const int w    = tid >> 6;
    const int cnt  = (int)gtCnt[c];
    const int nA   = (int)cursor[c * CPAD];

    // ---- per-lane GT slots, all registers -------------------------------
#define SLOTDECL(r)                                                \
    float gx1_##r, gy1_##r, gx2_##r, gy2_##r, ga_##r;              \
    u32 nm_##r;                                                    \
    u64 t0_##r = 0, t1_##r = 0, t2_##r = 0;
    SLOTDECL(0) SLOTDECL(1) SLOTDECL(2) SLOTDECL(3)

#define SLOTLOAD(r) {                                              \
    int s_ = lane + (r) * 64;                                      \
    if (s_ < cnt) {                                                \
        int m_ = gtIds[(size_t)c * MPAD + s_];                     \
        float4 g_ = gt[m_];                                        \
        gx1_##r = g_.x; gy1_##r = g_.y;                            \
        gx2_##r = g_.z; gy2_##r = g_.w;                            \
        ga_##r = (g_.z - g_.x) * (g_.w - g_.y);                    \
        nm_##r = ~(u32)m_;                                         \
    } else {                                                       \
        gx1_##r = gy1_##r = gx2_##r = gy2_##r = ga_##r = 0.f;      \
        nm_##r = 0u;   /* kb = 0: loses every max */               \
    } }
    SLOTLOAD(0) SLOTLOAD(1) SLOTLOAD(2) SLOTLOAD(3)

    // IoU expression verbatim (numpy-exact); pure register work.
#define SLOTPASS(r) {                                              \
    float ltx = fmaxf(ax, gx1_##r), lty = fmaxf(ay, gy1_##r);      \
    float rbx = fminf(az, gx2_##r), rby = fminf(aw, gy2_##r);      \
    float ww = fmaxf(rbx - ltx, 0.f), hh = fmaxf(rby - lty, 0.f);  \
    float inter = ww * hh;                                         \
    float iou = 0.f;                                               \
    if (inter > 0.f) iou = inter / ((area_a + ga_##r) - inter);    \
    u32 ibv_ = __float_as_uint(iou);                               \
    u64 kb_ = ((u64)ibv_ << 32) | nm_##r;                          \
    pa = kb_ > pa ? kb_ : pa;                                      \
    if (inter > 0.f) {                                             \
        u64 kt_ = ((u64)ibv_ << 32) | nai;                         \
        INS3(t0_##r, t1_##r, t2_##r, kt_);                         \
    } }

    const int nTiles = (nA + 255) >> 8;
    for (int tile = 0; tile < nTiles; ++tile) {
        int p = (tile << 8) + tid;
        int idx = (p < nA) ? binnedIdx[(size_t)c * CAP + p] : -1;
        float4 a = (idx >= 0) ? anchor[idx]
                              : make_float4(0.f, 0.f, 0.f, 0.f);
        __syncthreads();
        s_a[tid]    = a;
        s_area[tid] = (a.z - a.x) * (a.w - a.y);
        s_idx[tid]  = idx;
        __syncthreads();

        const int jb = w << 6;             // this wave's 64 staged anchors
        int myassign = -2;
        for (int jj = 0; jj < 64; ++jj) {
            int j = jb + jj;
            float4 A = s_a[j];             // broadcast LDS read
            float area_a = s_area[j];
            u32 nai = ~(u32)s_idx[j];      // idx=-1 -> nai=0 (never inserts)
            float ax = A.x, ay = A.y, az = A.z, aw = A.w;
            u64 pa = 0;

            SLOTPASS(0);
            if (cnt > 64)  SLOTPASS(1);    // cnt uniform: scalar branches
            if (cnt > 128) SLOTPASS(2);
            if (cnt > 192) SLOTPASS(3);

            for (int off = 1; off < 64; off <<= 1) {
                u64 o = shfl_xor_u64(pa, off);
                pa = o > pa ? o : pa;
            }
            u32 ibv = (u32)(pa >> 32);
            int v = -2;
            if (ibv < __float_as_uint(NEG_THRESH)) v = -1;
            if (ibv > __float_as_uint(POS_THRESH)) v = (int)(~(u32)pa);
            if (jj == lane) myassign = v;
        }
        int myidx = s_idx[jb + lane];
        if (myidx >= 0) out[myidx] = myassign;
    }

    // ---- merge register top-3 -> shadow (prefiltered cascade) -----------
    const int sh = blockIdx.x & (NSHADOW - 1);
#define SLOTMERGE(r) {                                             \
    int s_ = lane + (r) * 64;                                      \
    if (s_ < cnt) {                                                \
        int m_ = (int)(~nm_##r);                                   \
        u64* g3 = shadow3 + ((size_t)m_ * NSHADOW + sh) * SSTRIDE; \
        if ((u32)(t0_##r >> 32) != 0 && t0_##r > g3[2])            \
            CASCADE3(g3[0], g3[1], g3[2], t0_##r);                 \
        if ((u32)(t1_##r >> 32) != 0 && t1_##r > g3[2])            \
            CASCADE3(g3[0], g3[1], g3[2], t1_##r);                 \
        if ((u32)(t2_##r >> 32) != 0 && t2_##r > g3[2])            \
            CASCADE3(g3[0], g3[1], g3[2], t2_##r);                 \
    } }
    SLOTMERGE(0)
    if (cnt > 64)  SLOTMERGE(1)
    if (cnt > 128) SLOTMERGE(2)
    if (cnt > 192) SLOTMERGE(3)
}

// ---------------------------------------------------------------------------
// Claims: accumulate per-GT top-3 from seeds + 16 shadows, then forced-claim
// scatter-max via the proven 1024-slot LDS hash (tag CAS + 64-bit atomicMax).
// claim key = (anchor<<32)|(gt+1); max key == last-writer gt == reference.
__global__ void __launch_bounds__(256) k_claims(
    const u64* __restrict__ shadow3, int* __restrict__ out, int M)
{
    __shared__ u64 s_key[3 * MPAD];
    __shared__ u64 h_val[HSLOTS];
    __shared__ u32 h_tag[HSLOTS];   // anchor+1; 0 = empty
    const int tid = threadIdx.x;

    for (int i = tid; i < HSLOTS; i += 256) { h_val[i] = 0; h_tag[i] = 0; }

    if (tid < M) {
        // accumulators start at the zero-iou seeds (index-ordered fill)
        u64 q0 = 0x00000000FFFFFFFFULL;   // (iou=0, ~0)
        u64 q1 = 0x00000000FFFFFFFEULL;   // (iou=0, ~1)
        u64 q2 = 0x00000000FFFFFFFDULL;   // (iou=0, ~2)
        const u64* base = shadow3 + (size_t)tid * NSHADOW * SSTRIDE;
        for (int s = 0; s < NSHADOW; ++s) {
            const u64* p = base + (size_t)s * SSTRIDE;
            INS3(q0, q1, q2, p[0]);
            INS3(q0, q1, q2, p[1]);
            INS3(q0, q1, q2, p[2]);
        }

        float v0 = __uint_as_float((u32)(q0 >> 32));
        float v1 = __uint_as_float((u32)(q1 >> 32));
        float v2 = __uint_as_float((u32)(q2 >> 32));
        u32 a0 = ~(u32)q0;
        u32 a1 = ~(u32)q1;
        u32 a2 = ~(u32)q2;

        int npos = (v0 > POS_THRESH) + (v1 > POS_THRESH) + (v2 > POS_THRESH);
        bool low = npos < 3;

        s_key[tid * 3 + 0] = ((u64)a0 << 32) | (u32)(tid + 1);   // k==0 forced
        s_key[tid * 3 + 1] = (low && v1 > CLAIM_THRESH)
            ? (((u64)a1 << 32) | (u32)(tid + 1)) : 0ULL;
        s_key[tid * 3 + 2] = (low && v2 > CLAIM_THRESH)
            ? (((u64)a2 << 32) | (u32)(tid + 1)) : 0ULL;
    }
    __syncthreads();

    const int tote = 3 * M;
    // insert: claim slot by anchor tag, atomicMax the claim key
    for (int e = tid; e < tote; e += 256) {
        u64 my = s_key[e];
        if (my == 0) continue;
        u32 myA = (u32)(my >> 32);
        u32 slot = (myA * 2654435761u) & (HSLOTS - 1);
        while (true) {
            u32 prev = atomicCAS(&h_tag[slot], 0u, myA + 1u);
            if (prev == 0u || prev == myA + 1u) {
                atomicMax(&h_val[slot], my);
                break;
            }
            slot = (slot + 1) & (HSLOTS - 1);
        }
    }
    __syncthreads();
    // resolve: claim wins iff it holds the max key for its anchor
    for (int e = tid; e < tote; e += 256) {
        u64 my = s_key[e];
        if (my == 0) continue;
        u32 myA = (u32)(my >> 32);
        u32 slot = (myA * 2654435761u) & (HSLOTS - 1);
        while (h_tag[slot] != myA + 1u) slot = (slot + 1) & (HSLOTS - 1);
        if (h_val[slot] == my) out[myA] = (int)(my & 0xffffffffULL) - 1;
    }
}

// ---------------------------------------------------------------------------
extern "C" void kernel_launch(void* const* d_in, const int* in_sizes, int n_in,
                              void* d_out, int out_size, void* d_ws, size_t ws_size,
                              hipStream_t stream) {
    const float4* anchor = (const float4*)d_in[0];
    const float4* gt     = (const float4*)d_in[1];
    int N = in_sizes[0] / 4;
    int M = in_sizes[1] / 4;
    int* out = (int*)d_out;

    // workspace layout (~8.6 MB; ws_size ~= 256 MB)
    char* ws = (char*)d_ws;
    size_t off = 0;
    auto alloc = [&](size_t bytes, size_t align) -> void* {
        off = (off + align - 1) / align * align;
        void* p = ws + off;
        off += bytes;
        return p;
    };
    u32* gtCnt     = (u32*)alloc(NCELL * 4, 64);
    u32* cursor    = (u32*)alloc((size_t)NCELL * CPAD * 4, 64);
    u64* shadow3   = (u64*)alloc((size_t)MPAD * NSHADOW * SSTRIDE * 8, 64);
    u8*  gtIds     = (u8*)alloc((size_t)NCELL * MPAD, 16);
    int* binnedIdx = (int*)alloc((size_t)NCELL * CAP * 4, 16);

    int nb = (N + 255) / 256;
    k_prep<<<1, 256, 0, stream>>>(gt, gtCnt, gtIds, cursor, shadow3, M);
    k_scatidx<<<nb, 256, 0, stream>>>(anchor, cursor, binnedIdx, N);
    k_walk<<<NCELL, 256, 0, stream>>>(anchor, gt, gtCnt, gtIds, cursor,
                                      binnedIdx, shadow3, out, M);
    k_claims<<<1, 256, 0, stream>>>(shadow3, out, M);
}

// Round 22
// 140.223 us; speedup vs baseline: 1.8661x; 1.3865x over previous
//
#include <hip/hip_runtime.h>
#include <stdint.h>

// S3FD anchor assignment — per-cell dual-phase walk, round 22.
// d_in[0]: anchor [N,4] f32, d_in[1]: gt [M,4] f32. d_out: assign [N] int32.
//
// Round 21 post-mortem: the per-anchor u64 butterfly (12 dependent
// ds_bpermute, ~480 cy) serialized the jj-loop -> 150 us. Round 22: NO
// cross-lane ops at all. One kernel, two phases per 64-anchor chunk, each
// with its natural layout:
//   phase 1 (assign): thread-per-anchor register max; wave-uniform k-loop
//     over the cell's GTs via conflict-free LDS broadcasts (r20's assign).
//   phase 2 (top-3):  lane-per-GT register INS3 over the wave's 64 staged
//     anchors (r21's insert, butterfly deleted).
// IoU is computed twice but both phases are pure VALU (~27 instr/anchor).
// Waves are independent (private 64-slot LDS stage; no barriers in loop).
// Epilogue: r21's register -> 16-shadow prefiltered cascade.
// prep/scatidx/claims byte-identical to rounds 20/21 (passing).
//
// Key encoding (exact jax semantics), per-GT top-3:
//   key = (iou_bits << 32) | ~anchor_idx    (stable top_k: higher iou, then
//                                            lower anchor index wins)
// Seeds (0,~0),(0,~1),(0,~2) reproduce the reference's index-ordered zero
// fill (benign-duplication argument proven rounds 8-21). All reductions
// (max, top-3, cascade) are insertion-order-independent -> deterministic
// output despite nondeterministic scatter order.

typedef unsigned int u32;
typedef unsigned char u8;
typedef unsigned long long u64;

#define POS_THRESH 0.5f
#define NEG_THRESH 0.3f
#define CLAIM_THRESH 0.1f

constexpr int NCX = 32, NCY = 32, NCELL = NCX * NCY;  // 32x32 cells, 32 px
constexpr float INV_CELL = 0.03125f;                  // 1/32
constexpr float MARGIN = 64.5f;   // max anchor half-extent (<64.001) + slack
constexpr int MPAD = 256;         // padded GT count (M = 200); id stride
constexpr int HSLOTS = 1024;      // claims hash table slots
constexpr int NSHADOW = 16;       // shadow copies of final3
constexpr int SSTRIDE = 8;        // u64 per (GT,shadow) slot = 64B line
constexpr int CPAD = 16;          // u32 stride per cursor = one 64B line
constexpr int CAP = 2048;         // anchor slots per cell (lambda ~488)

#define INS3(t0, t1, t2, k) do {                                  \
    if ((k) > (t2)) {                                             \
        if ((k) > (t0))      { t2 = t1; t1 = t0; t0 = (k); }      \
        else if ((k) > (t1)) { t2 = t1; t1 = (k); }               \
        else                 { t2 = (k); }                        \
    } } while (0)

__device__ __forceinline__ int cell_of(const float4 a) {
    float cx = 0.5f * (a.x + a.z);
    float cy = 0.5f * (a.y + a.w);
    int ix = (int)(cx * INV_CELL);
    int iy = (int)(cy * INV_CELL);
    ix = ix < 0 ? 0 : (ix > NCX - 1 ? NCX - 1 : ix);
    iy = iy < 0 ? 0 : (iy > NCY - 1 ? NCY - 1 : iy);
    return iy * NCX + ix;
}

__device__ __forceinline__ void gt_range(const float4 g, int& clx, int& chx,
                                         int& cly, int& chy) {
    clx = (int)floorf((g.x - MARGIN) * INV_CELL);
    chx = (int)floorf((g.z + MARGIN) * INV_CELL);
    cly = (int)floorf((g.y - MARGIN) * INV_CELL);
    chy = (int)floorf((g.w + MARGIN) * INV_CELL);
    clx = clx < 0 ? 0 : (clx > NCX - 1 ? NCX - 1 : clx);
    chx = chx < 0 ? 0 : (chx > NCX - 1 ? NCX - 1 : chx);
    cly = cly < 0 ? 0 : (cly > NCY - 1 ? NCY - 1 : cly);
    chy = chy < 0 ? 0 : (chy > NCY - 1 ? NCY - 1 : chy);
}

// Concurrent sorted top-3 insert: atomicMax cascade (proven rounds 15-21).
#define CASCADE3(p0, p1, p2, key) {                               \
    u64 x_ = (key);                                               \
    u64 o_ = atomicMax(&(p0), x_); x_ = o_ < x_ ? o_ : x_;        \
    o_ = atomicMax(&(p1), x_); x_ = o_ < x_ ? o_ : x_;            \
    atomicMax(&(p2), x_);                                         \
}

// ---------------------------------------------------------------------------
// Prep (1 block): per-cell GT lists (u8 ids, stride MPAD) + zero cursors
// and shadow tables.
__global__ void __launch_bounds__(256) k_prep(
    const float4* __restrict__ gt, u32* __restrict__ gtCnt,
    u8* __restrict__ gtIds, u32* __restrict__ cursor,
    u64* __restrict__ shadow3, int M)
{
    __shared__ u32 l_cnt[NCELL];
    const int tid = threadIdx.x;
    for (int c = tid; c < NCELL; c += 256) l_cnt[c] = 0;

    for (int e = tid; e < NCELL * CPAD; e += 256) cursor[e] = 0;
    for (int e = tid; e < M * NSHADOW; e += 256) {
        u64* slot = shadow3 + (size_t)e * SSTRIDE;
        slot[0] = 0; slot[1] = 0; slot[2] = 0;
    }
    __syncthreads();

    if (tid < M) {
        float4 g = gt[tid];
        int clx, chx, cly, chy;
        gt_range(g, clx, chx, cly, chy);
        for (int iy = cly; iy <= chy; ++iy)
            for (int ix = clx; ix <= chx; ++ix) {
                int c = iy * NCX + ix;
                u32 slot = atomicAdd(&l_cnt[c], 1u);
                gtIds[(size_t)c * MPAD + slot] = (u8)tid;
            }
    }
    __syncthreads();
    for (int c = tid; c < NCELL; c += 256) gtCnt[c] = l_cnt[c];
}

// ---------------------------------------------------------------------------
// Scatter anchor INDICES into per-cell slot arrays (padded atomic cursors).
__global__ void __launch_bounds__(256) k_scatidx(
    const float4* __restrict__ anchor, u32* __restrict__ cursor,
    int* __restrict__ binnedIdx, int N)
{
    int i = blockIdx.x * 256 + threadIdx.x;
    if (i >= N) return;
    int c = cell_of(anchor[i]);
    u32 pos = atomicAdd(&cursor[c * CPAD], 1u);
    binnedIdx[(size_t)c * CAP + pos] = i;
}

// ---------------------------------------------------------------------------
// Walk (NCELL blocks x 256): block = cell. Per wave, per 64-anchor chunk:
//  phase 1: each lane's anchor in registers; wave-uniform k-loop over the
//           cell's GTs (LDS broadcasts) -> register argmax -> out[].
//  phase 2: stage the 64 anchors in the wave's PRIVATE LDS region; jj-loop
//           broadcasts each anchor; each lane INS3s into its GT slot's
//           register top-3. No cross-lane ops, no atomics, no barriers.
// Epilogue: register top-3 -> shadow (blockIdx & 15), prefiltered cascade.
__global__ void __launch_bounds__(256) k_walk(
    const float4* __restrict__ anchor, const float4* __restrict__ gt,
    const u32* __restrict__ gtCnt, const u8* __restrict__ gtIds,
    const u32* __restrict__ cursor, const int* __restrict__ binnedIdx,
    u64* __restrict__ shadow3, int* __restrict__ out, int M)
{
    __shared__ float4 s_gb[MPAD];
    __shared__ float  s_ga[MPAD];
    __shared__ u32    s_nm[MPAD];      // ~m per slot
    __shared__ float4 s_a[256];        // per-wave private 64-slot regions
    __shared__ float  s_area[256];
    __shared__ u32    s_nai[256];
    const int c    = blockIdx.x;
    const int tid  = threadIdx.x;
    const int lane = tid & 63;
    const int w    = tid >> 6;
    const int cnt  = (int)gtCnt[c];
    const int nA   = (int)cursor[c * CPAD];

    // cell GT table (shared by all waves; one barrier, before the loop)
    if (tid < cnt) {
        int m = gtIds[(size_t)c * MPAD + tid];
        float4 g = gt[m];
        s_gb[tid] = g;
        s_ga[tid] = (g.z - g.x) * (g.w - g.y);
        s_nm[tid] = ~(u32)m;
    }
    __syncthreads();

    // per-lane GT slots for phase 2, all registers
#define SLOTDECL(r)                                                \
    float gx1_##r, gy1_##r, gx2_##r, gy2_##r, ga_##r;              \
    u32 nm_##r;                                                    \
    u64 t0_##r = 0, t1_##r = 0, t2_##r = 0;
    SLOTDECL(0) SLOTDECL(1) SLOTDECL(2) SLOTDECL(3)

#define SLOTLOAD(r) {                                              \
    int s_ = lane + (r) * 64;                                      \
    if (s_ < cnt) {                                                \
        float4 g_ = s_gb[s_];                                      \
        gx1_##r = g_.x; gy1_##r = g_.y;                            \
        gx2_##r = g_.z; gy2_##r = g_.w;                            \
        ga_##r = s_ga[s_];                                         \
        nm_##r = s_nm[s_];                                         \
    } else {                                                       \
        gx1_##r = gy1_##r = gx2_##r = gy2_##r = ga_##r = 0.f;      \
        nm_##r = 0u;                                               \
    } }
    SLOTLOAD(0) SLOTLOAD(1) SLOTLOAD(2) SLOTLOAD(3)

    // phase-2 body: IoU of broadcast anchor (Ax..Aarea,Anai) vs lane's slot
#define SLOTP2(r) {                                                \
    float ltx = fmaxf(Ax, gx1_##r), lty = fmaxf(Ay, gy1_##r);      \
    float rbx = fminf(Az, gx2_##r), rby = fminf(Aw, gy2_##r);      \
    float ww = fmaxf(rbx - ltx, 0.f), hh = fmaxf(rby - lty, 0.f);  \
    float inter = ww * hh;                                         \
    if (inter > 0.f) {                                             \
        float iou = inter / ((Aarea + ga_##r) - inter);            \
        u64 kt_ = ((u64)__float_as_uint(iou) << 32) | Anai;        \
        INS3(t0_##r, t1_##r, t2_##r, kt_);                         \
    } }

    const int sbase = w << 6;              // wave's private stage base
    for (int p0 = sbase; p0 < nA; p0 += 256) {
        int p = p0 + lane;
        int idx = (p < nA) ? binnedIdx[(size_t)c * CAP + p] : -1;
        float4 a = (idx >= 0) ? anchor[idx]
                              : make_float4(0.f, 0.f, 0.f, 0.f);
        float area_a = (a.z - a.x) * (a.w - a.y);

        // ---- phase 1: assign (thread-per-anchor, broadcast GT loop) -----
        u64 best = 0;
        for (int k = 0; k < cnt; ++k) {    // wave-uniform; broadcasts
            float4 g = s_gb[k];
            float ag = s_ga[k];
            float ltx = fmaxf(a.x, g.x), lty = fmaxf(a.y, g.y);
            float rbx = fminf(a.z, g.z), rby = fminf(a.w, g.w);
            float ww = fmaxf(rbx - ltx, 0.f), hh = fmaxf(rby - lty, 0.f);
            float inter = ww * hh;
            if (inter > 0.f) {
                float iou = inter / ((area_a + ag) - inter);
                u64 kb = ((u64)__float_as_uint(iou) << 32) | s_nm[k];
                best = kb > best ? kb : best;
            }
        }
        if (idx >= 0) {
            u32 ibv = (u32)(best >> 32);
            int v = -2;
            if (ibv < __float_as_uint(NEG_THRESH)) v = -1;
            if (ibv > __float_as_uint(POS_THRESH)) v = (int)(~(u32)best);
            out[idx] = v;
        }

        // ---- phase 2: top-3 (lane-per-GT, wave-private stage) -----------
        s_a[tid]    = a;
        s_area[tid] = area_a;
        s_nai[tid]  = (idx >= 0) ? ~(u32)idx : 0u;
        // same-wave LDS write->read: no barrier needed
        for (int jj = 0; jj < 64; ++jj) {
            float4 A = s_a[sbase + jj];    // broadcast
            float Aarea = s_area[sbase + jj];
            u32 Anai = s_nai[sbase + jj];
            float Ax = A.x, Ay = A.y, Az = A.z, Aw = A.w;
            SLOTP2(0);
            if (cnt > 64)  SLOTP2(1);      // cnt uniform: scalar branches
            if (cnt > 128) SLOTP2(2);
            if (cnt > 192) SLOTP2(3);
        }
    }

    // ---- merge register top-3 -> shadow (prefiltered cascade) -----------
    const int sh = blockIdx.x & (NSHADOW - 1);
#define SLOTMERGE(r) {                                             \
    int s_ = lane + (r) * 64;                                      \
    if (s_ < cnt) {                                                \
        int m_ = (int)(~nm_##r);                                   \
        u64* g3 = shadow3 + ((size_t)m_ * NSHADOW + sh) * SSTRIDE; \
        if ((u32)(t0_##r >> 32) != 0 && t0_##r > g3[2])            \
            CASCADE3(g3[0], g3[1], g3[2], t0_##r);                 \
        if ((u32)(t1_##r >> 32) != 0 && t1_##r > g3[2])            \
            CASCADE3(g3[0], g3[1], g3[2], t1_##r);                 \
        if ((u32)(t2_##r >> 32) != 0 && t2_##r > g3[2])            \
            CASCADE3(g3[0], g3[1], g3[2], t2_##r);                 \
    } }
    SLOTMERGE(0)
    if (cnt > 64)  SLOTMERGE(1)
    if (cnt > 128) SLOTMERGE(2)
    if (cnt > 192) SLOTMERGE(3)
}

// ---------------------------------------------------------------------------
// Claims: accumulate per-GT top-3 from seeds + 16 shadows, then forced-claim
// scatter-max via the proven 1024-slot LDS hash (tag CAS + 64-bit atomicMax).
// claim key = (anchor<<32)|(gt+1); max key == last-writer gt == reference.
__global__ void __launch_bounds__(256) k_claims(
    const u64* __restrict__ shadow3, int* __restrict__ out, int M)
{
    __shared__ u64 s_key[3 * MPAD];
    __shared__ u64 h_val[HSLOTS];
    __shared__ u32 h_tag[HSLOTS];   // anchor+1; 0 = empty
    const int tid = threadIdx.x;

    for (int i = tid; i < HSLOTS; i += 256) { h_val[i] = 0; h_tag[i] = 0; }

    if (tid < M) {
        // accumulators start at the zero-iou seeds (index-ordered fill)
        u64 q0 = 0x00000000FFFFFFFFULL;   // (iou=0, ~0)
        u64 q1 = 0x00000000FFFFFFFEULL;   // (iou=0, ~1)
        u64 q2 = 0x00000000FFFFFFFDULL;   // (iou=0, ~2)
        const u64* base = shadow3 + (size_t)tid * NSHADOW * SSTRIDE;
        for (int s = 0; s < NSHADOW; ++s) {
            const u64* p = base + (size_t)s * SSTRIDE;
            INS3(q0, q1, q2, p[0]);
            INS3(q0, q1, q2, p[1]);
            INS3(q0, q1, q2, p[2]);
        }

        float v0 = __uint_as_float((u32)(q0 >> 32));
        float v1 = __uint_as_float((u32)(q1 >> 32));
        float v2 = __uint_as_float((u32)(q2 >> 32));
        u32 a0 = ~(u32)q0;
        u32 a1 = ~(u32)q1;
        u32 a2 = ~(u32)q2;

        int npos = (v0 > POS_THRESH) + (v1 > POS_THRESH) + (v2 > POS_THRESH);
        bool low = npos < 3;

        s_key[tid * 3 + 0] = ((u64)a0 << 32) | (u32)(tid + 1);   // k==0 forced
        s_key[tid * 3 + 1] = (low && v1 > CLAIM_THRESH)
            ? (((u64)a1 << 32) | (u32)(tid + 1)) : 0ULL;
        s_key[tid * 3 + 2] = (low && v2 > CLAIM_THRESH)
            ? (((u64)a2 << 32) | (u32)(tid + 1)) : 0ULL;
    }
    __syncthreads();

    const int tote = 3 * M;
    // insert: claim slot by anchor tag, atomicMax the claim key
    for (int e = tid; e < tote; e += 256) {
        u64 my = s_key[e];
        if (my == 0) continue;
        u32 myA = (u32)(my >> 32);
        u32 slot = (myA * 2654435761u) & (HSLOTS - 1);
        while (true) {
            u32 prev = atomicCAS(&h_tag[slot], 0u, myA + 1u);
            if (prev == 0u || prev == myA + 1u) {
                atomicMax(&h_val[slot], my);
                break;
            }
            slot = (slot + 1) & (HSLOTS - 1);
        }
    }
    __syncthreads();
    // resolve: claim wins iff it holds the max key for its anchor
    for (int e = tid; e < tote; e += 256) {
        u64 my = s_key[e];
        if (my == 0) continue;
        u32 myA = (u32)(my >> 32);
        u32 slot = (myA * 2654435761u) & (HSLOTS - 1);
        while (h_tag[slot] != myA + 1u) slot = (slot + 1) & (HSLOTS - 1);
        if (h_val[slot] == my) out[myA] = (int)(my & 0xffffffffULL) - 1;
    }
}

// ---------------------------------------------------------------------------
extern "C" void kernel_launch(void* const* d_in, const int* in_sizes, int n_in,
                              void* d_out, int out_size, void* d_ws, size_t ws_size,
                              hipStream_t stream) {
    const float4* anchor = (const float4*)d_in[0];
    const float4* gt     = (const float4*)d_in[1];
    int N = in_sizes[0] / 4;
    int M = in_sizes[1] / 4;
    int* out = (int*)d_out;

    // workspace layout (~8.6 MB; ws_size ~= 256 MB)
    char* ws = (char*)d_ws;
    size_t off = 0;
    auto alloc = [&](size_t bytes, size_t align) -> void* {
        off = (off + align - 1) / align * align;
        void* p = ws + off;
        off += bytes;
        return p;
    };
    u32* gtCnt     = (u32*)alloc(NCELL * 4, 64);
    u32* cursor    = (u32*)alloc((size_t)NCELL * CPAD * 4, 64);
    u64* shadow3   = (u64*)alloc((size_t)MPAD * NSHADOW * SSTRIDE * 8, 64);
    u8*  gtIds     = (u8*)alloc((size_t)NCELL * MPAD, 16);
    int* binnedIdx = (int*)alloc((size_t)NCELL * CAP * 4, 16);

    int nb = (N + 255) / 256;
    k_prep<<<1, 256, 0, stream>>>(gt, gtCnt, gtIds, cursor, shadow3, M);
    k_scatidx<<<nb, 256, 0, stream>>>(anchor, cursor, binnedIdx, N);
    k_walk<<<NCELL, 256, 0, stream>>>(anchor, gt, gtCnt, gtIds, cursor,
                                      binnedIdx, shadow3, out, M);
    k_claims<<<1, 256, 0, stream>>>(shadow3, out, M);
}